// Round 2
// baseline (535.669 us; speedup 1.0000x reference)
//
#include <hip/hip_runtime.h>
#include <hip/hip_bf16.h>
#include <math.h>

#define B_ROWS 65536
#define D_DIM 256
#define C_DIM 128
#define H_DIM 1024

typedef __bf16 bf16x8 __attribute__((ext_vector_type(8)));
typedef float f32x4 __attribute__((ext_vector_type(4)));
typedef short short8 __attribute__((ext_vector_type(8)));

__device__ __forceinline__ unsigned short f2bf(float f) {
    unsigned int u = __float_as_uint(f);
    u += 0x7fffu + ((u >> 16) & 1u);
    return (unsigned short)(u >> 16);
}

__device__ __forceinline__ void gl2lds16(const void* g, void* l) {
    __builtin_amdgcn_global_load_lds(
        (const __attribute__((address_space(1))) unsigned int*)g,
        (__attribute__((address_space(3))) unsigned int*)l, 16, 0, 0);
}

// Pack A1[r][c] bf16: c<128 -> x[r][2c] (even cols), else cond[r][c-128]
__global__ void prep_a1(const float* __restrict__ x, const float* __restrict__ cond,
                        short* __restrict__ A1) {
    int tid = blockIdx.x * 256 + threadIdx.x;
    int row = tid >> 5;
    int c8 = (tid & 31) << 3;
    float v[8];
    if (c8 < 128) {
        const float4* p = (const float4*)(x + (size_t)row * 256 + 2 * c8);
        float4 a = p[0], b = p[1], c = p[2], d = p[3];
        v[0]=a.x; v[1]=a.z; v[2]=b.x; v[3]=b.z; v[4]=c.x; v[5]=c.z; v[6]=d.x; v[7]=d.z;
    } else {
        const float4* p = (const float4*)(cond + (size_t)row * 128 + (c8 - 128));
        float4 a = p[0], b = p[1];
        v[0]=a.x; v[1]=a.y; v[2]=a.z; v[3]=a.w; v[4]=b.x; v[5]=b.y; v[6]=b.z; v[7]=b.w;
    }
    short8 o;
#pragma unroll
    for (int j = 0; j < 8; ++j) o[j] = (short)f2bf(v[j]);
    *(short8*)&A1[(size_t)row * 256 + c8] = o;
}

// dst[n*R + k] = bf16(src[k*C + n]); src is R x C row-major (K-major in), dst N x K
__global__ void transpose_bf16(const float* __restrict__ src, short* __restrict__ dst,
                               int R, int C, int total) {
    int tid = blockIdx.x * 256 + threadIdx.x;
    if (tid >= total) return;
    int per = R >> 3;
    int n = tid / per;
    int k0 = (tid - n * per) << 3;
    short8 o;
#pragma unroll
    for (int j = 0; j < 8; ++j) o[j] = (short)f2bf(src[(size_t)(k0 + j) * C + n]);
    *(short8*)&dst[(size_t)n * R + k0] = o;
}

__global__ void prep_b3(const float* __restrict__ bs, const float* __restrict__ bt,
                        float* __restrict__ b3) {
    int i = threadIdx.x;
    b3[i] = (i < 128) ? bs[i] : bt[i - 128];
}

// TN GEMM: A is M x K (row-major, K contiguous) bf16, Bw is N x K bf16.
// C[m][n] = sum_k A[m][k]*Bw[n][k] + bias[n].
// EPI 0: relu -> bf16 out. EPI 1: plain f32 out.
template <int EPI>
__global__ __launch_bounds__(256) void gemm_tn(
    const short* __restrict__ A, const short* __restrict__ Bw,
    const float* __restrict__ bias, void* __restrict__ Cout,
    int M, int N, int K) {
    constexpr int BM = 128, BN = 128, BK = 64;
    __shared__ __align__(16) short As[BM * BK];
    __shared__ __align__(16) short Bs[BN * BK];
    const int tid = threadIdx.x;
    const int lane = tid & 63;
    const int wave = tid >> 6;
    const int tm = blockIdx.y * BM;
    const int tn = blockIdx.x * BN;
    const int mo = (wave >> 1) * 64;
    const int no = (wave & 1) * 64;

    f32x4 acc[4][4];
#pragma unroll
    for (int i = 0; i < 4; ++i)
#pragma unroll
        for (int j = 0; j < 4; ++j) acc[i][j] = f32x4{0.f, 0.f, 0.f, 0.f};

    const int srow = lane >> 3;              // 0..7 row within 8-row chunk
    const int skb = (lane & 7) ^ srow;       // swizzled global k-block (16B units)

    for (int kc = 0; kc < K; kc += BK) {
        __syncthreads();
#pragma unroll
        for (int i = 0; i < 4; ++i) {
            int c = wave * 4 + i;            // chunk 0..15, rows 8c..8c+7
            int row = c * 8 + srow;
            gl2lds16(A + (size_t)(tm + row) * K + kc + skb * 8, &As[c * 512]);
            gl2lds16(Bw + (size_t)(tn + row) * K + kc + skb * 8, &Bs[c * 512]);
        }
        __syncthreads();
#pragma unroll
        for (int kk = 0; kk < 2; ++kk) {
            bf16x8 af[4], bfr[4];
            int kb = kk * 4 + (lane >> 4);
#pragma unroll
            for (int t = 0; t < 4; ++t) {
                int r = mo + t * 16 + (lane & 15);
                af[t] = *(const bf16x8*)&As[r * BK + ((kb ^ (r & 7)) << 3)];
                int n = no + t * 16 + (lane & 15);
                bfr[t] = *(const bf16x8*)&Bs[n * BK + ((kb ^ (n & 7)) << 3)];
            }
#pragma unroll
            for (int i = 0; i < 4; ++i)
#pragma unroll
                for (int j = 0; j < 4; ++j)
                    acc[i][j] = __builtin_amdgcn_mfma_f32_16x16x32_bf16(
                        af[i], bfr[j], acc[i][j], 0, 0, 0);
        }
    }

#pragma unroll
    for (int j = 0; j < 4; ++j) {
        int col = tn + no + j * 16 + (lane & 15);
        float bb = bias[col];
#pragma unroll
        for (int i = 0; i < 4; ++i) {
            int row0 = tm + mo + i * 16 + ((lane >> 4) << 2);
            f32x4 v = acc[i][j];
#pragma unroll
            for (int rr = 0; rr < 4; ++rr) {
                float val = v[rr] + bb;
                if (EPI == 0) {
                    val = fmaxf(val, 0.f);
                    ((unsigned short*)Cout)[(size_t)(row0 + rr) * N + col] = f2bf(val);
                } else {
                    ((float*)Cout)[(size_t)(row0 + rr) * N + col] = val;
                }
            }
        }
    }
}

// One wave per row: P[row] = [ls_pre(128) | t(128)], produce out + log_det
__global__ void finalize(const float* __restrict__ P, const float* __restrict__ x,
                         float* __restrict__ out, float* __restrict__ logdet) {
    int row = blockIdx.x * 4 + (threadIdx.x >> 6);
    int lane = threadIdx.x & 63;
    const float* Pr = P + (size_t)row * 256;
    const float* xr = x + (size_t)row * 256;
    float* outr = out + (size_t)row * 256;
    float sum = 0.f;
#pragma unroll
    for (int ii = 0; ii < 2; ++ii) {
        int i = lane + ii * 64;
        float ls = tanhf(Pr[i]);
        float t = Pr[128 + i];
        float2 xv = *(const float2*)&xr[2 * i];
        float2 ov;
        ov.x = xv.x;
        ov.y = xv.y * expf(ls) + t;
        *(float2*)&outr[2 * i] = ov;
        sum += ls;
    }
#pragma unroll
    for (int off = 32; off; off >>= 1) sum += __shfl_down(sum, off);
    if (lane == 0) logdet[row] = sum;
}

extern "C" void kernel_launch(void* const* d_in, const int* in_sizes, int n_in,
                              void* d_out, int out_size, void* d_ws, size_t ws_size,
                              hipStream_t stream) {
    const float* x = (const float*)d_in[0];
    const float* cond = (const float*)d_in[1];
    const float* W1 = (const float*)d_in[2];
    const float* b1 = (const float*)d_in[3];
    const float* W2 = (const float*)d_in[4];
    const float* b2 = (const float*)d_in[5];
    const float* Wsp = (const float*)d_in[6];
    const float* bs = (const float*)d_in[7];
    const float* Wtp = (const float*)d_in[8];
    const float* bt = (const float*)d_in[9];

    char* ws = (char*)d_ws;
    // Fixed region: transposed weights + fused bias.
    short* W1T = (short*)(ws);                          // 1024x256 bf16 = 512 KB
    short* W2T = (short*)(ws + 524288ull);              // 1024x1024 bf16 = 2 MB
    short* W3T = (short*)(ws + 2621440ull);             // 256x1024 bf16 = 512 KB
    float* b3  = (float*)(ws + 3145728ull);             // 1 KB
    const size_t chunk_base = 3149824ull;               // 4K-aligned

    // Choose largest row-chunk R' (power-of-2 divisor of 65536, >=128) whose
    // scratch footprint fits ws_size. Per-chunk: A1=512R', H1=2048R', H2=2048R'.
    int n_chunks = 1;
    while (n_chunks < 512) {
        size_t rp = (size_t)B_ROWS / n_chunks;
        if (chunk_base + rp * 4608ull <= ws_size) break;
        n_chunks *= 2;
    }
    const size_t RP = (size_t)B_ROWS / n_chunks;

    float* out = (float*)d_out;
    float* logdet = out + (size_t)B_ROWS * D_DIM;

    // One-time weight prep.
    transpose_bf16<<<(32768 + 255) / 256, 256, 0, stream>>>(W1, W1T, 256, 1024, 32768);
    transpose_bf16<<<(131072 + 255) / 256, 256, 0, stream>>>(W2, W2T, 1024, 1024, 131072);
    transpose_bf16<<<(16384 + 255) / 256, 256, 0, stream>>>(Wsp, W3T, 1024, 128, 16384);
    transpose_bf16<<<(16384 + 255) / 256, 256, 0, stream>>>(Wtp, W3T + 131072, 1024, 128, 16384);
    prep_b3<<<1, 256, 0, stream>>>(bs, bt, b3);

    for (int c = 0; c < n_chunks; ++c) {
        const size_t r0 = (size_t)c * RP;
        short* A1 = (short*)(ws + chunk_base);                 // 512*RP bytes
        short* H1 = (short*)(ws + chunk_base + 512ull * RP);   // 2048*RP
        float* P  = (float*)(ws + chunk_base + 512ull * RP);   // overlays dead H1
        short* H2 = (short*)(ws + chunk_base + 2560ull * RP);  // 2048*RP

        const float* xc = x + r0 * D_DIM;
        const float* cc = cond + r0 * C_DIM;

        prep_a1<<<RP / 8, 256, 0, stream>>>(xc, cc, A1);
        gemm_tn<0><<<dim3(H_DIM / 128, RP / 128), 256, 0, stream>>>(
            A1, W1T, b1, H1, (int)RP, H_DIM, 256);
        gemm_tn<0><<<dim3(H_DIM / 128, RP / 128), 256, 0, stream>>>(
            H1, W2T, b2, H2, (int)RP, H_DIM, 1024);
        gemm_tn<1><<<dim3(256 / 128, RP / 128), 256, 0, stream>>>(
            H2, W3T, b3, P, (int)RP, 256, 1024);
        finalize<<<RP / 4, 256, 0, stream>>>(P, xc, out + r0 * D_DIM, logdet + r0);
    }
}